// Round 1
// baseline (594.428 us; speedup 1.0000x reference)
//
#include <hip/hip_runtime.h>
#include <cstdint>
#include <cstddef>

#define NB 64
#define NPG 50
#define EPG 2048
#define NN 3200
#define NE 131072
#define DLIN 1024
#define DCONV 12544
#define DTOT 13568
#define DREL 256
#define NP 50
#define NK 10
#define NX 100
#define BK 32
#define BM 64
#define KSPLIT 8
#define KCH (DTOT / KSPLIT)   /* 1696 = 53 tiles of 32 */
#define NTILES (EPG / BM)     /* 32 tiles per graph */

/* ws layout in floats */
#define WS_NODE  0
#define WS_PMAX  (NN * NP)                     /* 160000 */
#define WS_PARG  (WS_PMAX + NB * NTILES * NP)  /* 262400 (int32) */
#define WS_ACOL  (WS_PARG + NB * NTILES * NP)  /* 364800 */
#define WS_RCOL  (WS_ACOL + NP)                /* 364850 */
#define WS_PNODE (WS_RCOL + NP)                /* 364900 .. +8*160000 */

/* out layout in floats */
#define O_SC  0
#define O_SRC 6400
#define O_DST 12800
#define O_PSC 19200
#define O_PCL 25600
#define O_NR  32000

/* ---------------- per-class L1 column sums ---------------- */
__global__ __launch_bounds__(256) void k_colsums(const float* __restrict__ Wobj,
                                                 const float* __restrict__ Wconv,
                                                 const float* __restrict__ Wrel,
                                                 float* __restrict__ Acol,
                                                 float* __restrict__ Rcol) {
    int c = blockIdx.x;          // 0..49
    int t = threadIdx.x;         // 0..255
    float a = 0.f;
    for (int d = t; d < DLIN; d += 256)  a += fabsf(Wobj[d * NP + c]);
    for (int d = t; d < DCONV; d += 256) a += fabsf(Wconv[d * NP + c]);
    float r = 0.f;
    for (int d = t; d < DREL; d += 256)  r += fabsf(Wrel[d * NP + c]);
    __shared__ float sa[256], sr[256];
    sa[t] = a; sr[t] = r;
    __syncthreads();
    for (int s = 128; s > 0; s >>= 1) {
        if (t < s) { sa[t] += sa[t + s]; sr[t] += sr[t + s]; }
        __syncthreads();
    }
    if (t == 0) { Acol[c] = sa[0]; Rcol[c] = sr[0]; }
}

/* ---------------- node GEMM (split-K partials) ----------------
   node = obj_lin(3200x1024)@W_obj + conv(3200x12544)@W_conv
   grid (50, 8), 256 threads; tile BM=64 rows x 50 cols, BK=32 */
__global__ __launch_bounds__(256) void k_node(const float* __restrict__ objlin,
                                              const float* __restrict__ objconv,
                                              const float* __restrict__ Wobj,
                                              const float* __restrict__ Wconv,
                                              float* __restrict__ pnode) {
    const int mb = blockIdx.x;        // 0..49
    const int ks = blockIdx.y;        // 0..7
    const int m0 = mb * BM;
    const int tid = threadIdx.x;
    const int tx = tid & 15, ty = tid >> 4;

    __shared__ __align__(16) float At[BM][BK + 4];   // stride 36 floats
    __shared__ __align__(16) float Wt[BK][NP + 2];   // stride 52 floats

    float acc[4][4] = {};

    for (int kt = 0; kt < KCH / BK; ++kt) {
        int kg = ks * KCH + kt * BK;
        const float* Aptr; int lda; int ko; const float* Wp;
        if (kg < DLIN) { Aptr = objlin; lda = DLIN; ko = kg; Wp = Wobj + kg * NP; }
        else { Aptr = objconv; lda = DCONV; ko = kg - DLIN; Wp = Wconv + (size_t)(kg - DLIN) * NP; }

        __syncthreads();
        /* stage A tile: 64 rows x 32 k = 512 float4, 2 per thread */
        #pragma unroll
        for (int rep = 0; rep < 2; ++rep) {
            int lin = tid + rep * 256;
            int r = lin >> 3, q = lin & 7;
            float4 v = *(const float4*)(Aptr + (size_t)(m0 + r) * lda + ko + q * 4);
            *(float4*)&At[r][q * 4] = v;
        }
        /* stage W tile: 32x50 contiguous */
        for (int i = tid; i < BK * NP; i += 256) {
            Wt[i / NP][i % NP] = Wp[i];
        }
        __syncthreads();

        #pragma unroll
        for (int k4 = 0; k4 < BK; k4 += 4) {
            float ar[4][4];
            #pragma unroll
            for (int i = 0; i < 4; ++i) {
                float4 t4 = *(const float4*)&At[ty * 4 + i][k4];
                ar[i][0] = t4.x; ar[i][1] = t4.y; ar[i][2] = t4.z; ar[i][3] = t4.w;
            }
            #pragma unroll
            for (int kk = 0; kk < 4; ++kk) {
                float4 wv = *(const float4*)&Wt[k4 + kk][tx * 4];
                float w0 = wv.x, w1 = wv.y, w2 = wv.z, w3 = wv.w;
                #pragma unroll
                for (int i = 0; i < 4; ++i) {
                    float a = ar[i][kk];
                    acc[i][0] = fmaf(a, w0, acc[i][0]);
                    acc[i][1] = fmaf(a, w1, acc[i][1]);
                    acc[i][2] = fmaf(a, w2, acc[i][2]);
                    acc[i][3] = fmaf(a, w3, acc[i][3]);
                }
            }
        }
    }

    float* out = pnode + (size_t)ks * (NN * NP);
    #pragma unroll
    for (int i = 0; i < 4; ++i) {
        int row = m0 + ty * 4 + i;
        #pragma unroll
        for (int j = 0; j < 4; ++j) {
            int c = tx * 4 + j;
            if (c < NP) out[row * NP + c] = acc[i][j];
        }
    }
}

/* deterministic split-K combine */
__global__ __launch_bounds__(256) void k_combine(const float* __restrict__ pnode,
                                                 float* __restrict__ node) {
    int i = blockIdx.x * 256 + threadIdx.x;
    if (i < NN * NP) {
        float s = 0.f;
        #pragma unroll
        for (int ks = 0; ks < KSPLIT; ++ks) s += pnode[(size_t)ks * (NN * NP) + i];
        node[i] = s;
    }
}

/* ---------------- edge GEMM + gather + per-tile max/argmax ----------------
   edge = rel_lin(131072x256)@W_rel + node[src] + node[dst]
   grid 2048 blocks (64 edges each), 256 threads */
__global__ __launch_bounds__(256) void k_edge(const float* __restrict__ rellin,
                                              const float* __restrict__ Wrel,
                                              const float* __restrict__ node,
                                              const int* __restrict__ relidx,
                                              float* __restrict__ pmax,
                                              int* __restrict__ parg) {
    const int blk = blockIdx.x;       // global tile 0..2047
    const int e0 = blk * BM;
    const int tid = threadIdx.x;
    const int tx = tid & 15, ty = tid >> 4;

    __shared__ __align__(16) float At[BM][BK + 4];
    __shared__ __align__(16) float Wt[BK][NP + 2];
    __shared__ float redv[16][64];
    __shared__ int   rede[16][64];

    float acc[4][4] = {};

    for (int kt = 0; kt < DREL / BK; ++kt) {   // 8 tiles
        int kg = kt * BK;
        __syncthreads();
        #pragma unroll
        for (int rep = 0; rep < 2; ++rep) {
            int lin = tid + rep * 256;
            int r = lin >> 3, q = lin & 7;
            float4 v = *(const float4*)(rellin + (size_t)(e0 + r) * DREL + kg + q * 4);
            *(float4*)&At[r][q * 4] = v;
        }
        const float* Wp = Wrel + kg * NP;
        for (int i = tid; i < BK * NP; i += 256) {
            Wt[i / NP][i % NP] = Wp[i];
        }
        __syncthreads();

        #pragma unroll
        for (int k4 = 0; k4 < BK; k4 += 4) {
            float ar[4][4];
            #pragma unroll
            for (int i = 0; i < 4; ++i) {
                float4 t4 = *(const float4*)&At[ty * 4 + i][k4];
                ar[i][0] = t4.x; ar[i][1] = t4.y; ar[i][2] = t4.z; ar[i][3] = t4.w;
            }
            #pragma unroll
            for (int kk = 0; kk < 4; ++kk) {
                float4 wv = *(const float4*)&Wt[k4 + kk][tx * 4];
                float w0 = wv.x, w1 = wv.y, w2 = wv.z, w3 = wv.w;
                #pragma unroll
                for (int i = 0; i < 4; ++i) {
                    float a = ar[i][kk];
                    acc[i][0] = fmaf(a, w0, acc[i][0]);
                    acc[i][1] = fmaf(a, w1, acc[i][1]);
                    acc[i][2] = fmaf(a, w2, acc[i][2]);
                    acc[i][3] = fmaf(a, w3, acc[i][3]);
                }
            }
        }
    }

    /* gather node rows for this thread's 4 edges */
    int srcs[4], dsts[4];
    #pragma unroll
    for (int i = 0; i < 4; ++i) {
        int eg = e0 + ty * 4 + i;
        srcs[i] = relidx[eg];
        dsts[i] = relidx[NE + eg];
    }
    #pragma unroll
    for (int j = 0; j < 4; ++j) {
        int c = tx * 4 + j;
        if (c < NP) {
            float bv = -3.4e38f; int be = 0;
            #pragma unroll
            for (int i = 0; i < 4; ++i) {
                float v = acc[i][j] + node[srcs[i] * NP + c] + node[dsts[i] * NP + c];
                if (v > bv) { bv = v; be = e0 + ty * 4 + i; }   // strict >: lowest edge wins ties
            }
            redv[ty][c] = bv; rede[ty][c] = be;
        }
    }
    __syncthreads();
    if (tid < NP) {
        float bv = -3.4e38f; int be = 0;
        #pragma unroll
        for (int t2 = 0; t2 < 16; ++t2) {
            float v = redv[t2][tid];
            if (v > bv) { bv = v; be = rede[t2][tid]; }
        }
        pmax[blk * NP + tid] = bv;
        parg[blk * NP + tid] = be;
    }
}

/* ---------------- per-graph: reduce, sigmoid, top-10, score, emit 100 rows ---------------- */
__global__ __launch_bounds__(64) void k_graph(const float* __restrict__ pmax,
                                              const int* __restrict__ parg,
                                              const float* __restrict__ Acol,
                                              const float* __restrict__ Rcol,
                                              const int* __restrict__ relidx,
                                              float* __restrict__ out) {
    const int b = blockIdx.x;     // 0..63
    const int lane = threadIdx.x; // 0..63

    __shared__ float prob[NP];
    __shared__ int   earg[NP];
    __shared__ float psc[NK]; __shared__ int pcl[NK];
    __shared__ float sc[NK];  __shared__ int fl[NK];
    __shared__ int   order[NK];
    __shared__ int   rflat[NX]; __shared__ float rsc[NX];

    if (lane < NP) {
        float v = -3.4e38f; int e = 0;
        for (int t = 0; t < NTILES; ++t) {
            float pv = pmax[(b * NTILES + t) * NP + lane];
            if (pv > v) { v = pv; e = parg[(b * NTILES + t) * NP + lane]; }
        }
        prob[lane] = 1.f / (1.f + expf(-v));
        earg[lane] = e;
    }
    __syncthreads();

    if (lane == 0) {
        unsigned long long used = 0ull;
        for (int k = 0; k < NK; ++k) {
            float best = -1.f; int bc = 0;
            for (int c = 0; c < NP; ++c) {
                if (!((used >> c) & 1ull) && prob[c] > best) { best = prob[c]; bc = c; }
            }
            used |= (1ull << bc);
            psc[k] = best; pcl[k] = bc;
            float s = best, g = s * (1.f - s);
            int e = earg[bc];
            int sN = relidx[e], dN = relidx[NE + e];
            float f = (sN == dN) ? 4.f : 1.f;
            float A = Acol[bc], R = Rcol[bc];
            sc[k] = f * g * g * g * A * A * R * s;
            fl[k] = (e - b * EPG) * NK + k;
        }
        for (int k = 0; k < NK; ++k) order[k] = k;
        for (int i = 0; i < NK; ++i)
            for (int j = i + 1; j < NK; ++j) {
                int a = order[i], c = order[j];
                if (sc[c] > sc[a] || (sc[c] == sc[a] && fl[c] < fl[a])) { order[i] = c; order[j] = a; }
            }
        for (int x = 0; x < NK; ++x) { rflat[x] = fl[order[x]]; rsc[x] = sc[order[x]]; }
        /* 90 zero rows: smallest flat indices not used by the nonzeros (JAX tie-break) */
        int x = NK, f = 0;
        while (x < NX) {
            bool hit = false;
            for (int k = 0; k < NK; ++k) if (fl[k] == f) { hit = true; break; }
            if (!hit) { rflat[x] = f; rsc[x] = 0.f; ++x; }
            ++f;
        }
    }
    __syncthreads();

    for (int x = lane; x < NX; x += 64) {
        int flat = rflat[x];
        int el = flat / NK, k = flat % NK;
        int eg = b * EPG + el;
        int row = b * NX + x;
        out[O_SC  + row] = rsc[x];
        out[O_SRC + row] = (float)relidx[eg];
        out[O_DST + row] = (float)relidx[NE + eg];
        out[O_PSC + row] = psc[k];
        out[O_PCL + row] = (float)pcl[k];
    }
    if (lane == 0) out[O_NR + b] = (float)NX;
}

extern "C" void kernel_launch(void* const* d_in, const int* in_sizes, int n_in,
                              void* d_out, int out_size, void* d_ws, size_t ws_size,
                              hipStream_t stream) {
    const float* objlin  = (const float*)d_in[0];
    const float* objconv = (const float*)d_in[1];
    const float* rellin  = (const float*)d_in[2];
    const int*   relidx  = (const int*)d_in[3];
    const float* Wobj    = (const float*)d_in[4];
    const float* Wconv   = (const float*)d_in[5];
    const float* Wrel    = (const float*)d_in[6];

    float* ws    = (float*)d_ws;
    float* node  = ws + WS_NODE;
    float* pmax  = ws + WS_PMAX;
    int*   parg  = (int*)(ws + WS_PARG);
    float* Acol  = ws + WS_ACOL;
    float* Rcol  = ws + WS_RCOL;
    float* pnode = ws + WS_PNODE;
    float* out   = (float*)d_out;

    hipLaunchKernelGGL(k_colsums, dim3(NP), dim3(256), 0, stream, Wobj, Wconv, Wrel, Acol, Rcol);
    hipLaunchKernelGGL(k_node, dim3(NN / BM, KSPLIT), dim3(256), 0, stream,
                       objlin, objconv, Wobj, Wconv, pnode);
    hipLaunchKernelGGL(k_combine, dim3((NN * NP + 255) / 256), dim3(256), 0, stream, pnode, node);
    hipLaunchKernelGGL(k_edge, dim3(NE / BM), dim3(256), 0, stream,
                       rellin, Wrel, node, relidx, pmax, parg);
    hipLaunchKernelGGL(k_graph, dim3(NB), dim3(64), 0, stream, pmax, parg, Acol, Rcol, relidx, out);
}

// Round 2
// 518.175 us; speedup vs baseline: 1.1472x; 1.1472x over previous
//
#include <hip/hip_runtime.h>
#include <cstdint>
#include <cstddef>

#define NB 64
#define NPG 50
#define EPG 2048
#define NN 3200
#define NE 131072
#define DLIN 1024
#define DCONV 12544
#define DTOT 13568
#define DREL 256
#define NP 50
#define NK 10
#define NX 100
#define BK 32
#define BM 64
#define KSPLIT 53
#define KCH (DTOT / KSPLIT)   /* 256 floats per chunk = 8 tiles of 32; k=1024 boundary at ks=4 */
#define NTILES (EPG / BM)     /* 32 tiles per graph */

/* ws layout in floats */
#define WS_NODE  0
#define WS_PMAX  (NN * NP)                     /* 160000 */
#define WS_PARG  (WS_PMAX + NB * NTILES * NP)  /* 262400 (int32) */
#define WS_ACOL  (WS_PARG + NB * NTILES * NP)  /* 364800 */
#define WS_RCOL  (WS_ACOL + NP)                /* 364850 */
#define WS_PNODE (WS_RCOL + NP)                /* 364900 .. +53*160000 floats (~35 MB) */

/* out layout in floats */
#define O_SC  0
#define O_SRC 6400
#define O_DST 12800
#define O_PSC 19200
#define O_PCL 25600
#define O_NR  32000

/* ---------------- per-class L1 column sums ---------------- */
__global__ __launch_bounds__(256) void k_colsums(const float* __restrict__ Wobj,
                                                 const float* __restrict__ Wconv,
                                                 const float* __restrict__ Wrel,
                                                 float* __restrict__ Acol,
                                                 float* __restrict__ Rcol) {
    int c = blockIdx.x;          // 0..49
    int t = threadIdx.x;         // 0..255
    float a = 0.f;
    for (int d = t; d < DLIN; d += 256)  a += fabsf(Wobj[d * NP + c]);
    for (int d = t; d < DCONV; d += 256) a += fabsf(Wconv[d * NP + c]);
    float r = 0.f;
    for (int d = t; d < DREL; d += 256)  r += fabsf(Wrel[d * NP + c]);
    __shared__ float sa[256], sr[256];
    sa[t] = a; sr[t] = r;
    __syncthreads();
    for (int s = 128; s > 0; s >>= 1) {
        if (t < s) { sa[t] += sa[t + s]; sr[t] += sr[t + s]; }
        __syncthreads();
    }
    if (t == 0) { Acol[c] = sa[0]; Rcol[c] = sr[0]; }
}

/* ---------------- node GEMM (split-K partials) ----------------
   node = obj_lin(3200x1024)@W_obj + conv(3200x12544)@W_conv
   grid (50, 53), 256 threads; tile BM=64 rows x 50 cols, BK=32, 8 k-tiles/block */
__global__ __launch_bounds__(256) void k_node(const float* __restrict__ objlin,
                                              const float* __restrict__ objconv,
                                              const float* __restrict__ Wobj,
                                              const float* __restrict__ Wconv,
                                              float* __restrict__ pnode) {
    const int mb = blockIdx.x;        // 0..49
    const int ks = blockIdx.y;        // 0..52
    const int m0 = mb * BM;
    const int tid = threadIdx.x;
    const int tx = tid & 15, ty = tid >> 4;

    __shared__ __align__(16) float At[BM][BK + 4];   // stride 36 floats
    __shared__ __align__(16) float Wt[BK][NP + 2];   // stride 52 floats

    /* resolve chunk -> matrix once per block (k=1024 boundary == ks 4 boundary) */
    const float* Aptr; int lda; int ko0; const float* Wb;
    if (ks < 4) { Aptr = objlin;  lda = DLIN;  ko0 = ks * KCH;        Wb = Wobj  + (size_t)(ks * KCH) * NP; }
    else        { Aptr = objconv; lda = DCONV; ko0 = ks * KCH - DLIN; Wb = Wconv + (size_t)(ks * KCH - DLIN) * NP; }

    float acc[4][4] = {};

    for (int kt = 0; kt < KCH / BK; ++kt) {   // 8 tiles
        int ko = ko0 + kt * BK;
        const float* Wp = Wb + (size_t)(kt * BK) * NP;

        __syncthreads();
        /* stage A tile: 64 rows x 32 k = 512 float4, 2 per thread */
        #pragma unroll
        for (int rep = 0; rep < 2; ++rep) {
            int lin = tid + rep * 256;
            int r = lin >> 3, q = lin & 7;
            float4 v = *(const float4*)(Aptr + (size_t)(m0 + r) * lda + ko + q * 4);
            *(float4*)&At[r][q * 4] = v;
        }
        /* stage W tile: 32x50 contiguous */
        for (int i = tid; i < BK * NP; i += 256) {
            Wt[i / NP][i % NP] = Wp[i];
        }
        __syncthreads();

        #pragma unroll
        for (int k4 = 0; k4 < BK; k4 += 4) {
            float ar[4][4];
            #pragma unroll
            for (int i = 0; i < 4; ++i) {
                float4 t4 = *(const float4*)&At[ty * 4 + i][k4];
                ar[i][0] = t4.x; ar[i][1] = t4.y; ar[i][2] = t4.z; ar[i][3] = t4.w;
            }
            #pragma unroll
            for (int kk = 0; kk < 4; ++kk) {
                float4 wv = *(const float4*)&Wt[k4 + kk][tx * 4];
                float w0 = wv.x, w1 = wv.y, w2 = wv.z, w3 = wv.w;
                #pragma unroll
                for (int i = 0; i < 4; ++i) {
                    float a = ar[i][kk];
                    acc[i][0] = fmaf(a, w0, acc[i][0]);
                    acc[i][1] = fmaf(a, w1, acc[i][1]);
                    acc[i][2] = fmaf(a, w2, acc[i][2]);
                    acc[i][3] = fmaf(a, w3, acc[i][3]);
                }
            }
        }
    }

    float* out = pnode + (size_t)ks * (NN * NP);
    #pragma unroll
    for (int i = 0; i < 4; ++i) {
        int row = m0 + ty * 4 + i;
        #pragma unroll
        for (int j = 0; j < 4; ++j) {
            int c = tx * 4 + j;
            if (c < NP) out[row * NP + c] = acc[i][j];
        }
    }
}

/* deterministic split-K combine: node = sum of 53 partials */
__global__ __launch_bounds__(256) void k_combine(const float* __restrict__ pnode,
                                                 float* __restrict__ node) {
    int i = blockIdx.x * 256 + threadIdx.x;
    if (i < NN * NP) {
        float s = 0.f;
        for (int ks = 0; ks < KSPLIT; ++ks) s += pnode[(size_t)ks * (NN * NP) + i];
        node[i] = s;
    }
}

/* ---------------- edge GEMM + LDS node gather + per-tile max/argmax ----------------
   edge = rel_lin(131072x256)@W_rel + node[src] + node[dst]
   grid 2048 blocks (64 edges each, all in one graph), 256 threads */
__global__ __launch_bounds__(256) void k_edge(const float* __restrict__ rellin,
                                              const float* __restrict__ Wrel,
                                              const float* __restrict__ node,
                                              const int* __restrict__ relidx,
                                              float* __restrict__ pmax,
                                              int* __restrict__ parg) {
    const int blk = blockIdx.x;       // global tile 0..2047
    const int e0 = blk * BM;
    const int b  = blk >> 5;          // graph id (32 tiles per graph)
    const int tid = threadIdx.x;
    const int tx = tid & 15, ty = tid >> 4;

    /* union: {At,Wt} for the K-loop, node_s for the epilogue */
    __shared__ __align__(16) char smem[15872];
    float (*At)[BK + 4]     = (float(*)[BK + 4])smem;            // [64][36] = 9216 B
    float (*Wt)[NP + 2]     = (float(*)[NP + 2])(smem + 9216);   // [32][52] = 6656 B
    float (*node_s)[NP + 2] = (float(*)[NP + 2])smem;            // [50][52] = 10400 B (epilogue)
    __shared__ float redv[16][64];
    __shared__ int   rede[16][64];

    float acc[4][4] = {};

    for (int kt = 0; kt < DREL / BK; ++kt) {   // 8 tiles
        int kg = kt * BK;
        __syncthreads();
        #pragma unroll
        for (int rep = 0; rep < 2; ++rep) {
            int lin = tid + rep * 256;
            int r = lin >> 3, q = lin & 7;
            float4 v = *(const float4*)(rellin + (size_t)(e0 + r) * DREL + kg + q * 4);
            *(float4*)&At[r][q * 4] = v;
        }
        const float* Wp = Wrel + (size_t)kg * NP;
        for (int i = tid; i < BK * NP; i += 256) {
            Wt[i / NP][i % NP] = Wp[i];
        }
        __syncthreads();

        #pragma unroll
        for (int k4 = 0; k4 < BK; k4 += 4) {
            float ar[4][4];
            #pragma unroll
            for (int i = 0; i < 4; ++i) {
                float4 t4 = *(const float4*)&At[ty * 4 + i][k4];
                ar[i][0] = t4.x; ar[i][1] = t4.y; ar[i][2] = t4.z; ar[i][3] = t4.w;
            }
            #pragma unroll
            for (int kk = 0; kk < 4; ++kk) {
                float4 wv = *(const float4*)&Wt[k4 + kk][tx * 4];
                float w0 = wv.x, w1 = wv.y, w2 = wv.z, w3 = wv.w;
                #pragma unroll
                for (int i = 0; i < 4; ++i) {
                    float a = ar[i][kk];
                    acc[i][0] = fmaf(a, w0, acc[i][0]);
                    acc[i][1] = fmaf(a, w1, acc[i][1]);
                    acc[i][2] = fmaf(a, w2, acc[i][2]);
                    acc[i][3] = fmaf(a, w3, acc[i][3]);
                }
            }
        }
    }

    /* ---- epilogue: stage this graph's node slab (50x50) into LDS ---- */
    __syncthreads();   // all At/Wt reads done
    {
        const float* nb = node + (size_t)b * NPG * NP;
        for (int i = tid; i < NPG * NP; i += 256) {
            node_s[i / NP][i % NP] = nb[i];
        }
    }
    __syncthreads();

    /* local node ids for this thread's 4 edges */
    int sl[4], dl[4];
    #pragma unroll
    for (int i = 0; i < 4; ++i) {
        int eg = e0 + ty * 4 + i;
        sl[i] = relidx[eg]      - b * NPG;
        dl[i] = relidx[NE + eg] - b * NPG;
    }
    #pragma unroll
    for (int j = 0; j < 4; ++j) {
        int c = tx * 4 + j;
        if (c < NP) {
            float bv = -3.4e38f; int be = 0;
            #pragma unroll
            for (int i = 0; i < 4; ++i) {
                float v = acc[i][j] + node_s[sl[i]][c] + node_s[dl[i]][c];
                if (v > bv) { bv = v; be = e0 + ty * 4 + i; }   // strict >: lowest edge wins ties
            }
            redv[ty][c] = bv; rede[ty][c] = be;
        }
    }
    __syncthreads();
    if (tid < NP) {
        float bv = -3.4e38f; int be = 0;
        #pragma unroll
        for (int t2 = 0; t2 < 16; ++t2) {
            float v = redv[t2][tid];
            if (v > bv) { bv = v; be = rede[t2][tid]; }
        }
        pmax[blk * NP + tid] = bv;
        parg[blk * NP + tid] = be;
    }
}

/* ---------------- per-graph: reduce, sigmoid, top-10, score, emit 100 rows ---------------- */
__global__ __launch_bounds__(64) void k_graph(const float* __restrict__ pmax,
                                              const int* __restrict__ parg,
                                              const float* __restrict__ Acol,
                                              const float* __restrict__ Rcol,
                                              const int* __restrict__ relidx,
                                              float* __restrict__ out) {
    const int b = blockIdx.x;     // 0..63
    const int lane = threadIdx.x; // 0..63

    __shared__ float prob[NP];
    __shared__ int   earg[NP];
    __shared__ float psc[NK]; __shared__ int pcl[NK];
    __shared__ float sc[NK];  __shared__ int fl[NK];
    __shared__ int   order[NK];
    __shared__ int   rflat[NX]; __shared__ float rsc[NX];

    if (lane < NP) {
        float v = -3.4e38f; int e = 0;
        for (int t = 0; t < NTILES; ++t) {
            float pv = pmax[(b * NTILES + t) * NP + lane];
            if (pv > v) { v = pv; e = parg[(b * NTILES + t) * NP + lane]; }
        }
        prob[lane] = 1.f / (1.f + expf(-v));
        earg[lane] = e;
    }
    __syncthreads();

    if (lane == 0) {
        unsigned long long used = 0ull;
        for (int k = 0; k < NK; ++k) {
            float best = -1.f; int bc = 0;
            for (int c = 0; c < NP; ++c) {
                if (!((used >> c) & 1ull) && prob[c] > best) { best = prob[c]; bc = c; }
            }
            used |= (1ull << bc);
            psc[k] = best; pcl[k] = bc;
            float s = best, g = s * (1.f - s);
            int e = earg[bc];
            int sN = relidx[e], dN = relidx[NE + e];
            float f = (sN == dN) ? 4.f : 1.f;
            float A = Acol[bc], R = Rcol[bc];
            sc[k] = f * g * g * g * A * A * R * s;
            fl[k] = (e - b * EPG) * NK + k;
        }
        for (int k = 0; k < NK; ++k) order[k] = k;
        for (int i = 0; i < NK; ++i)
            for (int j = i + 1; j < NK; ++j) {
                int a = order[i], c = order[j];
                if (sc[c] > sc[a] || (sc[c] == sc[a] && fl[c] < fl[a])) { order[i] = c; order[j] = a; }
            }
        for (int x = 0; x < NK; ++x) { rflat[x] = fl[order[x]]; rsc[x] = sc[order[x]]; }
        /* 90 zero rows: smallest flat indices not used by the nonzeros (JAX tie-break) */
        int x = NK, f = 0;
        while (x < NX) {
            bool hit = false;
            for (int k = 0; k < NK; ++k) if (fl[k] == f) { hit = true; break; }
            if (!hit) { rflat[x] = f; rsc[x] = 0.f; ++x; }
            ++f;
        }
    }
    __syncthreads();

    for (int x = lane; x < NX; x += 64) {
        int flat = rflat[x];
        int el = flat / NK, k = flat % NK;
        int eg = b * EPG + el;
        int row = b * NX + x;
        out[O_SC  + row] = rsc[x];
        out[O_SRC + row] = (float)relidx[eg];
        out[O_DST + row] = (float)relidx[NE + eg];
        out[O_PSC + row] = psc[k];
        out[O_PCL + row] = (float)pcl[k];
    }
    if (lane == 0) out[O_NR + b] = (float)NX;
}

extern "C" void kernel_launch(void* const* d_in, const int* in_sizes, int n_in,
                              void* d_out, int out_size, void* d_ws, size_t ws_size,
                              hipStream_t stream) {
    const float* objlin  = (const float*)d_in[0];
    const float* objconv = (const float*)d_in[1];
    const float* rellin  = (const float*)d_in[2];
    const int*   relidx  = (const int*)d_in[3];
    const float* Wobj    = (const float*)d_in[4];
    const float* Wconv   = (const float*)d_in[5];
    const float* Wrel    = (const float*)d_in[6];

    float* ws    = (float*)d_ws;
    float* node  = ws + WS_NODE;
    float* pmax  = ws + WS_PMAX;
    int*   parg  = (int*)(ws + WS_PARG);
    float* Acol  = ws + WS_ACOL;
    float* Rcol  = ws + WS_RCOL;
    float* pnode = ws + WS_PNODE;
    float* out   = (float*)d_out;

    hipLaunchKernelGGL(k_colsums, dim3(NP), dim3(256), 0, stream, Wobj, Wconv, Wrel, Acol, Rcol);
    hipLaunchKernelGGL(k_node, dim3(NN / BM, KSPLIT), dim3(256), 0, stream,
                       objlin, objconv, Wobj, Wconv, pnode);
    hipLaunchKernelGGL(k_combine, dim3((NN * NP + 255) / 256), dim3(256), 0, stream, pnode, node);
    hipLaunchKernelGGL(k_edge, dim3(NE / BM), dim3(256), 0, stream,
                       rellin, Wrel, node, relidx, pmax, parg);
    hipLaunchKernelGGL(k_graph, dim3(NB), dim3(64), 0, stream, pmax, parg, Acol, Rcol, relidx, out);
}